// Round 3
// baseline (431.612 us; speedup 1.0000x reference)
//
#include <hip/hip_runtime.h>
#include <hip/hip_bf16.h>
#include <stdint.h>

#define BATCH 8192
#define DIM   2048
#define NEXP  8
#define BM    128
#define BN    128
#define BK    32
#define NITER (DIM / BK)   // 64
#define MAX_TILES 72
#define NBLK  (DIM / BN)   // 16
#define NCVTB 4096         // W cvt blocks: 8*2048*2048*2B / 16B / (512thr*2chunks)

typedef __bf16 bf16x8 __attribute__((ext_vector_type(8)));
typedef float  f32x4  __attribute__((ext_vector_type(4)));

// ---- workspace layout ----
// tile metadata in ws[0..511]; rowmap@512 (ints); Wb (bf16) @ byte 37,789,696
#define WB_BYTE_OFF 37789696ull
#define WS_NEED     104898560ull

#define AS1(p) ((const __attribute__((address_space(1))) void*)(p))
#define AS3(p) ((__attribute__((address_space(3))) void*)(p))

__device__ __forceinline__ unsigned f2bf2(float lo, float hi) {
    unsigned ul = __float_as_uint(lo), uh = __float_as_uint(hi);
    ul = (ul + 0x7FFFu + ((ul >> 16) & 1u)) >> 16;   // RNE
    uh = (uh + 0x7FFFu + ((uh >> 16) & 1u)) >> 16;
    return (uh << 16) | ul;
}

// Merged prep:
//   block 0          : routing plan (histogram -> per-expert wave-parallel
//                      scan via shfl -> tiles -> rowmap). No atomics.
//   blocks [1,NCVTB] : W fp32 -> bf16, 32B in / 16B out per thread per chunk.
// Plan (~10us) hides under the W conversion stream (~55us).
__global__ __launch_bounds__(512)
void k_prep(const int* __restrict__ ids, int* __restrict__ ws,
            int* __restrict__ rowmap,
            const float4* __restrict__ W, uint4* __restrict__ Wb) {
    int b = blockIdx.x;
    int t = threadIdx.x;
    if (b > 0) {
        // ---- W conversion ----
        size_t base = (size_t)(b - 1) * 1024;   // uint4 index
#pragma unroll
        for (int j = 0; j < 2; j++) {
            size_t o = base + (size_t)j * 512 + t;
            float4 a = W[o * 2], c = W[o * 2 + 1];
            uint4 v;
            v.x = f2bf2(a.x, a.y);  v.y = f2bf2(a.z, a.w);
            v.z = f2bf2(c.x, c.y);  v.w = f2bf2(c.z, c.w);
            Wb[o] = v;
        }
        return;
    }
    // ---- routing plan (single block, 512 threads = 8 waves) ----
    __shared__ int sc[512 * NEXP];   // per-thread per-expert counts -> prefixes
    __shared__ int seg[NEXP];
    __shared__ int tot[NEXP];
    int myids[16];
    int base = t * 16;               // each thread owns 16 consecutive rows
#pragma unroll
    for (int e = 0; e < NEXP; e++) sc[t * NEXP + e] = 0;
#pragma unroll
    for (int i = 0; i < 16; i++) {
        myids[i] = ids[base + i];
        sc[t * NEXP + myids[i]]++;
    }
    __syncthreads();
    // wave w computes exclusive prefix over the 512 counts of expert w
    {
        int w = t >> 6, l = t & 63;
        int e = w;                   // 8 waves == NEXP
        int vals[8], sum = 0;
#pragma unroll
        for (int j = 0; j < 8; j++) { vals[j] = sc[(l * 8 + j) * NEXP + e]; sum += vals[j]; }
        int inc = sum;
        for (int d = 1; d < 64; d <<= 1) {
            int v = __shfl_up(inc, d, 64);
            if (l >= d) inc += v;
        }
        int run = inc - sum;         // exclusive
#pragma unroll
        for (int j = 0; j < 8; j++) { int v = vals[j]; sc[(l * 8 + j) * NEXP + e] = run; run += v; }
        if (l == 63) tot[e] = run;
    }
    __syncthreads();
    if (t == 0) {
        int pos = 0, mt = 0;
        for (int e = 0; e < NEXP; e++) {
            int c = tot[e];
            seg[e] = pos;
            int ntl = (c + BM - 1) / BM;
            for (int tt = 0; tt < ntl; tt++) {
                ws[64  + mt] = e;
                ws[160 + mt] = pos + tt * BM;
                int v = c - tt * BM;
                ws[256 + mt] = v < BM ? v : BM;
                mt++;
            }
            pos += ntl * BM;
        }
        ws[48] = mt;
    }
    __syncthreads();
#pragma unroll
    for (int i = 0; i < 16; i++) {
        int e = myids[i];
        int p = seg[e] + sc[t * NEXP + e]++;
        rowmap[p] = base + i;
    }
}

// grouped GEMM: 128x128 tile, 4 waves (2x2 of 64x64), BK=32,
// DOUBLE-BUFFERED LDS, round-0 proven schedule (single barrier/iter,
// prefetch i+1 during compute i; __syncthreads drains vmcnt+lgkmcnt).
// B: global_load_lds with source-address swizzle (dest linear).
// A: FUSED GATHER — each lane reg-loads 16 fp32 from x (row via rowmap,
//    fixed per block), converts to bf16 (cvt_pk), ds_writes into the SAME
//    swizzled layout. A-loads issue BEFORE B gload_lds so the cvt waits on
//    a counted vmcnt(4) and B prefetch stays in flight. Rows >= valid stage
//    zeros (no zero-fill pass needed anywhere).
// Swizzle: 16B chunk at LDS position p of row r holds logical chunk
// p ^ ((r>>1)&3) -> 2-way (free) bank aliasing on ds_read_b128 phases.
// Grid: dim3(16,72) -> XCD = nb%8 (proven round-0 mapping: each 512KB
// B-panel owned by exactly one XCD, L2-resident across that expert's tiles).
__launch_bounds__(256)
__global__ void k_gemm(const float* __restrict__ x,
                       const unsigned short* __restrict__ Wb,
                       const float* __restrict__ bias,
                       const int* __restrict__ ws, const int* __restrict__ rowmap,
                       float* __restrict__ out) {
    int nb = blockIdx.x;              // n-block 0..15
    int mt = blockIdx.y;              // m-tile
    if (mt >= ws[48]) return;
    int e     = ws[64  + mt];
    int pos0  = ws[160 + mt];
    int valid = ws[256 + mt];
    int n0 = nb * BN;

    __shared__ unsigned short lds[2][8192];  // [buf][0..4095]=A, [4096..8191]=B; 32 KB

    int tid = threadIdx.x;
    int w = tid >> 6, l = tid & 63;
    int lane15 = l & 15, quad = l >> 4;
    int wave_m = (w >> 1) * 64, wave_n = (w & 1) * 64;

    const unsigned short* Bbase = Wb + (size_t)e * DIM * DIM + (size_t)n0 * DIM;

    // ---- A gather state (loop-invariant) ----
    int arow  = w * 32 + (l >> 1);     // tile row staged by this lane
    int ahalf = l & 1;                 // which 16-float half of the BK row
    int s_r = (arow >> 1) & 3;
    int aw0 = arow * BK + (((ahalf * 2)    ) ^ s_r) * 8;   // shorts
    int aw1 = arow * BK + (((ahalf * 2) + 1) ^ s_r) * 8;
    bool aval = arow < valid;
    const float4* asrc = nullptr;
    if (aval)
        asrc = (const float4*)(x + (size_t)rowmap[pos0 + arow] * DIM + ahalf * 16);

    // ---- B staging source offsets (shorts), invariant across K except +k0 ----
    int srcOff[2];
#pragma unroll
    for (int j = 0; j < 2; j++) {
        int c = w * 128 + j * 64 + l;
        int row = c >> 2, pos = c & 3;
        int q = pos ^ ((row >> 1) & 3);
        srcOff[j] = row * DIM + q * 8;
    }

    // fragment read offsets (shorts), loop-invariant.
    int swz = (quad ^ ((lane15 >> 1) & 3)) * 8;
    int afOff[4], bfOff[4];
#pragma unroll
    for (int mi = 0; mi < 4; mi++)
        afOff[mi] = (wave_m + mi * 16 + lane15) * BK + swz;
#pragma unroll
    for (int ni = 0; ni < 4; ni++)
        bfOff[ni] = 4096 + (wave_n + ni * 16 + lane15) * BK + swz;

    f32x4 acc[4][4];
#pragma unroll
    for (int i = 0; i < 4; i++)
#pragma unroll
        for (int j = 0; j < 4; j++) acc[i][j] = (f32x4){0.f, 0.f, 0.f, 0.f};

#define ISSUE_B(buf, k0)                                                        \
    do {                                                                        \
        _Pragma("unroll")                                                       \
        for (int j = 0; j < 2; j++) {                                           \
            __builtin_amdgcn_global_load_lds(                                   \
                AS1(Bbase + (k0) + srcOff[j]),                                  \
                AS3(&lds[buf][4096 + w * 1024 + j * 512]), 16, 0, 0);           \
        }                                                                       \
    } while (0)

#define CVT_WRITE(buf, a0, a1, a2, a3)                                          \
    do {                                                                        \
        bf16x8 c0, c1;                                                          \
        c0[0] = (__bf16)a0.x; c0[1] = (__bf16)a0.y;                             \
        c0[2] = (__bf16)a0.z; c0[3] = (__bf16)a0.w;                             \
        c0[4] = (__bf16)a1.x; c0[5] = (__bf16)a1.y;                             \
        c0[6] = (__bf16)a1.z; c0[7] = (__bf16)a1.w;                             \
        c1[0] = (__bf16)a2.x; c1[1] = (__bf16)a2.y;                             \
        c1[2] = (__bf16)a2.z; c1[3] = (__bf16)a2.w;                             \
        c1[4] = (__bf16)a3.x; c1[5] = (__bf16)a3.y;                             \
        c1[6] = (__bf16)a3.z; c1[7] = (__bf16)a3.w;                             \
        *(bf16x8*)(&lds[buf][aw0]) = c0;                                        \
        *(bf16x8*)(&lds[buf][aw1]) = c1;                                        \
    } while (0)

    // prologue: stage A(0) + issue B(0)
    {
        float4 a0 = {0,0,0,0}, a1 = {0,0,0,0}, a2 = {0,0,0,0}, a3 = {0,0,0,0};
        if (aval) { a0 = asrc[0]; a1 = asrc[1]; a2 = asrc[2]; a3 = asrc[3]; }
        CVT_WRITE(0, a0, a1, a2, a3);
        ISSUE_B(0, 0);
    }
    int cur = 0;
    for (int i = 0; i < NITER; ++i) {
        __syncthreads();   // drains vmcnt+lgkmcnt: B(i) landed, A(i) written,
                           // all compute(i-1) done -> buf cur^1 free.
        float4 a0 = {0,0,0,0}, a1 = {0,0,0,0}, a2 = {0,0,0,0}, a3 = {0,0,0,0};
        if (i + 1 < NITER) {
            if (aval) {                                  // A(i+1) -> regs (issued
                const float4* p = asrc + (i + 1) * (BK / 4);   // before B gloads)
                a0 = p[0]; a1 = p[1]; a2 = p[2]; a3 = p[3];
            }
            ISSUE_B(cur ^ 1, (i + 1) * BK);
        }
        bf16x8 af[4], bf[4];
#pragma unroll
        for (int mi = 0; mi < 4; mi++)
            af[mi] = *(const bf16x8*)(&lds[cur][afOff[mi]]);
#pragma unroll
        for (int ni = 0; ni < 4; ni++)
            bf[ni] = *(const bf16x8*)(&lds[cur][bfOff[ni]]);
#pragma unroll
        for (int mi = 0; mi < 4; mi++)
#pragma unroll
            for (int ni = 0; ni < 4; ni++)
                acc[mi][ni] = __builtin_amdgcn_mfma_f32_16x16x32_bf16(
                    af[mi], bf[ni], acc[mi][ni], 0, 0, 0);
        if (i + 1 < NITER)
            CVT_WRITE(cur ^ 1, a0, a1, a2, a3);          // waits vmcnt(4): A only
        cur ^= 1;
    }
#undef ISSUE_B
#undef CVT_WRITE

    // epilogue: bias + relu + residual (fp32, direct from x) + scatter
    float bv[4];
#pragma unroll
    for (int ni = 0; ni < 4; ni++)
        bv[ni] = bias[(size_t)e * DIM + n0 + wave_n + ni * 16 + lane15];
#pragma unroll
    for (int mi = 0; mi < 4; mi++) {
#pragma unroll
        for (int r4 = 0; r4 < 4; r4++) {
            int rl = wave_m + mi * 16 + quad * 4 + r4;
            if (rl < valid) {
                int orig = rowmap[pos0 + rl];
                const float* xrow = x + (size_t)orig * DIM + n0;
                float* orow = out + (size_t)orig * DIM + n0;
#pragma unroll
                for (int ni = 0; ni < 4; ni++) {
                    int col = wave_n + ni * 16 + lane15;
                    float v = acc[mi][ni][r4] + bv[ni];
                    v = v > 0.f ? v : 0.f;
                    orow[col] = xrow[col] + v;
                }
            }
        }
    }
}

// slow-but-correct fallback if workspace is too small
__global__ void k_naive(const float* __restrict__ x, const int* __restrict__ ids,
                        const float* __restrict__ W, const float* __restrict__ b,
                        float* __restrict__ out) {
    __shared__ float lx[DIM];
    int i = blockIdx.x;
    for (int t = threadIdx.x; t < DIM; t += blockDim.x) lx[t] = x[(size_t)i * DIM + t];
    __syncthreads();
    int e = ids[i];
    const float* We = W + (size_t)e * DIM * DIM;
    for (int n = threadIdx.x; n < DIM; n += blockDim.x) {
        const float* wr = We + (size_t)n * DIM;
        float acc = 0.f;
        for (int k = 0; k < DIM; k += 4) {
            float4 w4 = *(const float4*)(wr + k);
            acc += lx[k] * w4.x + lx[k + 1] * w4.y + lx[k + 2] * w4.z + lx[k + 3] * w4.w;
        }
        float v = acc + b[(size_t)e * DIM + n];
        v = v > 0.f ? v : 0.f;
        out[(size_t)i * DIM + n] = lx[n] + v;
    }
}

extern "C" void kernel_launch(void* const* d_in, const int* in_sizes, int n_in,
                              void* d_out, int out_size, void* d_ws, size_t ws_size,
                              hipStream_t stream) {
    const float* x   = (const float*)d_in[0];
    const int*   ids = (const int*)d_in[1];
    const float* W   = (const float*)d_in[2];
    const float* b   = (const float*)d_in[3];
    float* out = (float*)d_out;

    if (ws_size < WS_NEED) {
        k_naive<<<BATCH, 256, 0, stream>>>(x, ids, W, b, out);
        return;
    }

    char* wsb = (char*)d_ws;
    int*  wsi = (int*)wsb;
    unsigned short* Wb = (unsigned short*)(wsb + WB_BYTE_OFF);
    int* rowmap = wsi + 512;

    k_prep<<<NCVTB + 1, 512, 0, stream>>>(ids, wsi, rowmap,
                                          (const float4*)W, (uint4*)Wb);
    dim3 g(NBLK, MAX_TILES);
    k_gemm<<<g, 256, 0, stream>>>(x, Wb, b, wsi, rowmap, out);
}

// Round 4
// 407.610 us; speedup vs baseline: 1.0589x; 1.0589x over previous
//
#include <hip/hip_runtime.h>
#include <hip/hip_bf16.h>
#include <stdint.h>

#define BATCH 8192
#define DIM   2048
#define NEXP  8
#define BM    128
#define BN    128
#define BK    32
#define NITER (DIM / BK)   // 64
#define MAX_TILES 72
#define NBLK  (DIM / BN)   // 16
#define NROWS 9216         // BATCH + max padding (8*128)
#define NXBB  2048         // x cvt blocks:  8192*2048*2B /16B /(512thr*2chunks)
#define NCVTB 4096         // W cvt blocks: 8*2048*2048*2B /16B /(512thr*2chunks)

typedef __bf16 bf16x8 __attribute__((ext_vector_type(8)));
typedef float  f32x4  __attribute__((ext_vector_type(4)));

// ---- workspace layout ----
// metadata ints 0..511 (tileExp@64 tilePos0@160 tileVal@256 ntiles@48)
// rowmap @ int 512 (9216 ints, ends byte 38912)
// zeropage @ byte 40960 (4 KB of zeros; A-stage target for padding rows)
// xb (bf16, ORIGINAL row order) @ byte 49152 (33.5 MB)
// Wb (bf16) @ byte 37,789,696 (67 MB, ends exactly at WS_NEED)
#define ZP_BYTE_OFF 40960ull
#define XB_BYTE_OFF 49152ull
#define WB_BYTE_OFF 37789696ull
#define WS_NEED     104898560ull

#define AS1(p) ((const __attribute__((address_space(1))) void*)(p))
#define AS3(p) ((__attribute__((address_space(3))) void*)(p))

__device__ __forceinline__ unsigned f2bf2(float lo, float hi) {
    unsigned ul = __float_as_uint(lo), uh = __float_as_uint(hi);
    ul = (ul + 0x7FFFu + ((ul >> 16) & 1u)) >> 16;   // RNE
    uh = (uh + 0x7FFFu + ((uh >> 16) & 1u)) >> 16;
    return (uh << 16) | ul;
}

// ONE prep dispatch, no cross-block dependencies, no atomics:
//   block 0                  : routing plan (hist -> wave-parallel scan ->
//                              tiles -> rowmap) + zeropage fill
//   blocks [1, NXBB]         : x fp32 -> bf16 (ORIGINAL order -> independent
//                              of the plan)
//   blocks (NXBB, NXBB+NCVTB]: W fp32 -> bf16
// Plan (~10us) hides under ~300 MB of pure streaming.
__global__ __launch_bounds__(512)
void k_prep(const int* __restrict__ ids, int* __restrict__ ws,
            int* __restrict__ rowmap,
            const float4* __restrict__ x4, uint4* __restrict__ xb4,
            const float4* __restrict__ W, uint4* __restrict__ Wb,
            int* __restrict__ zp) {
    int b = blockIdx.x;
    int t = threadIdx.x;
    if (b > 0) {
        // ---- streaming fp32 -> bf16, 32B in / 16B out per thread per chunk
        const float4* src; uint4* dst; size_t base;
        if (b <= NXBB) { src = x4; dst = xb4; base = (size_t)(b - 1) * 1024; }
        else           { src = W;  dst = Wb;  base = (size_t)(b - 1 - NXBB) * 1024; }
#pragma unroll
        for (int j = 0; j < 2; j++) {
            size_t o = base + (size_t)j * 512 + t;
            float4 a = src[o * 2], c = src[o * 2 + 1];
            uint4 v;
            v.x = f2bf2(a.x, a.y);  v.y = f2bf2(a.z, a.w);
            v.z = f2bf2(c.x, c.y);  v.w = f2bf2(c.z, c.w);
            dst[o] = v;
        }
        return;
    }
    // ---- routing plan (single block, 512 threads = 8 waves) ----
    zp[t] = 0; zp[t + 512] = 0;      // 4 KB zero page
    __shared__ int sc[512 * NEXP];   // per-thread per-expert counts -> prefixes
    __shared__ int seg[NEXP];
    __shared__ int tot[NEXP];
    int myids[16];
    int base = t * 16;               // each thread owns 16 consecutive rows
#pragma unroll
    for (int e = 0; e < NEXP; e++) sc[t * NEXP + e] = 0;
#pragma unroll
    for (int i = 0; i < 16; i++) {
        myids[i] = ids[base + i];
        sc[t * NEXP + myids[i]]++;
    }
    __syncthreads();
    // wave w computes exclusive prefix over the 512 counts of expert w
    {
        int w = t >> 6, l = t & 63;
        int e = w;                   // 8 waves == NEXP
        int vals[8], sum = 0;
#pragma unroll
        for (int j = 0; j < 8; j++) { vals[j] = sc[(l * 8 + j) * NEXP + e]; sum += vals[j]; }
        int inc = sum;
        for (int d = 1; d < 64; d <<= 1) {
            int v = __shfl_up(inc, d, 64);
            if (l >= d) inc += v;
        }
        int run = inc - sum;         // exclusive
#pragma unroll
        for (int j = 0; j < 8; j++) { int v = vals[j]; sc[(l * 8 + j) * NEXP + e] = run; run += v; }
        if (l == 63) tot[e] = run;
    }
    __syncthreads();
    if (t == 0) {
        int pos = 0, mt = 0;
        for (int e = 0; e < NEXP; e++) {
            int c = tot[e];
            seg[e] = pos;
            int ntl = (c + BM - 1) / BM;
            for (int tt = 0; tt < ntl; tt++) {
                ws[64  + mt] = e;
                ws[160 + mt] = pos + tt * BM;
                int v = c - tt * BM;
                ws[256 + mt] = v < BM ? v : BM;
                mt++;
            }
            pos += ntl * BM;
        }
        ws[48] = mt;
    }
    __syncthreads();
    for (int i = t; i < NROWS; i += 512) rowmap[i] = -1;
    __syncthreads();                 // init drained before fills
#pragma unroll
    for (int i = 0; i < 16; i++) {
        int e = myids[i];
        int p = seg[e] + sc[t * NEXP + e]++;
        rowmap[p] = base + i;
    }
}

// grouped GEMM: 128x128 tile, 4 waves (2x2 of 64x64), BK=32,
// DOUBLE-BUFFERED LDS, round-0 PROVEN schedule (single barrier/iter,
// prefetch i+1 during compute i; __syncthreads drains vmcnt(0)).
// A and B both staged via global_load_lds (no reg round-trip -> nothing for
// the compiler to hoist). A's source address is PER-LANE (guide §5/m173):
// lane's row base = xb + rowmap[pos0+row]*DIM (zeropage for padding rows),
// so the gather happens inside the staging load itself -- xg is gone.
// Swizzle: 16B chunk at LDS position p of row r holds logical chunk
// p ^ ((r>>1)&3) -> 2-way (free) bank aliasing on ds_read_b128 phases,
// applied on the staging SOURCE address (dest stays wave-uniform linear).
// Grid: dim3(16,72) -> XCD = nb%8 (proven round-0 mapping: each 512KB
// B-panel owned by one XCD, L2-resident across that expert's m-tiles).
__launch_bounds__(256)
__global__ void k_gemm(const float* __restrict__ x,
                       const unsigned short* __restrict__ xb,
                       const unsigned short* __restrict__ Wb,
                       const unsigned short* __restrict__ zp,
                       const float* __restrict__ bias,
                       const int* __restrict__ ws, const int* __restrict__ rowmap,
                       float* __restrict__ out) {
    int nb = blockIdx.x;              // n-block 0..15
    int mt = blockIdx.y;              // m-tile
    if (mt >= ws[48]) return;
    int e     = ws[64  + mt];
    int pos0  = ws[160 + mt];
    int valid = ws[256 + mt];
    int n0 = nb * BN;

    __shared__ unsigned short lds[2][8192];  // [buf][0..4095]=A, [4096..8191]=B; 32 KB

    int tid = threadIdx.x;
    int w = tid >> 6, l = tid & 63;
    int lane15 = l & 15, quad = l >> 4;
    int wave_m = (w >> 1) * 64, wave_n = (w & 1) * 64;

    const unsigned short* Bbase = Wb + (size_t)e * DIM * DIM + (size_t)n0 * DIM;

    // staging addresses, loop-invariant except +k0.
    // tile side = 512 chunks of 16B; wave w stages chunks [w*128, w*128+128)
    // in 2 issues of 64. chunk c: row=c>>2, dest pos=c&3, src q=pos^((row>>1)&3).
    // A: per-lane row base through rowmap (padding rows -> zeropage).
    const unsigned short* aptr[2];
    int srcOffB[2];
#pragma unroll
    for (int j = 0; j < 2; j++) {
        int c = w * 128 + j * 64 + l;
        int row = c >> 2, pos = c & 3;
        int q = pos ^ ((row >> 1) & 3);
        int rm = rowmap[pos0 + row];
        const unsigned short* rb = (rm >= 0) ? (xb + (size_t)rm * DIM) : zp;
        aptr[j] = rb + q * 8;
        srcOffB[j] = row * DIM + q * 8;
    }

    // fragment read offsets (shorts), loop-invariant.
    int swz = (quad ^ ((lane15 >> 1) & 3)) * 8;
    int afOff[4], bfOff[4];
#pragma unroll
    for (int mi = 0; mi < 4; mi++)
        afOff[mi] = (wave_m + mi * 16 + lane15) * BK + swz;
#pragma unroll
    for (int ni = 0; ni < 4; ni++)
        bfOff[ni] = 4096 + (wave_n + ni * 16 + lane15) * BK + swz;

    f32x4 acc[4][4];
#pragma unroll
    for (int i = 0; i < 4; i++)
#pragma unroll
        for (int j = 0; j < 4; j++) acc[i][j] = (f32x4){0.f, 0.f, 0.f, 0.f};

#define ISSUE(buf, k0)                                                          \
    do {                                                                        \
        _Pragma("unroll")                                                       \
        for (int j = 0; j < 2; j++) {                                           \
            __builtin_amdgcn_global_load_lds(                                   \
                AS1(aptr[j] + (k0)),                                            \
                AS3(&lds[buf][w * 1024 + j * 512]), 16, 0, 0);                  \
            __builtin_amdgcn_global_load_lds(                                   \
                AS1(Bbase + (k0) + srcOffB[j]),                                 \
                AS3(&lds[buf][4096 + w * 1024 + j * 512]), 16, 0, 0);           \
        }                                                                       \
    } while (0)

    ISSUE(0, 0);
    int cur = 0;
    for (int i = 0; i < NITER; ++i) {
        __syncthreads();   // drains vmcnt(0): loads(i) complete (in flight
                           // during compute(i-1)); all compute(i-1) done.
        if (i + 1 < NITER) {
            int k0n = (i + 1) * BK;
            ISSUE(cur ^ 1, k0n);
        }
        bf16x8 af[4], bf[4];
#pragma unroll
        for (int mi = 0; mi < 4; mi++)
            af[mi] = *(const bf16x8*)(&lds[cur][afOff[mi]]);
#pragma unroll
        for (int ni = 0; ni < 4; ni++)
            bf[ni] = *(const bf16x8*)(&lds[cur][bfOff[ni]]);
#pragma unroll
        for (int mi = 0; mi < 4; mi++)
#pragma unroll
            for (int ni = 0; ni < 4; ni++)
                acc[mi][ni] = __builtin_amdgcn_mfma_f32_16x16x32_bf16(
                    af[mi], bf[ni], acc[mi][ni], 0, 0, 0);
        cur ^= 1;
    }
#undef ISSUE

    // epilogue: bias + relu + residual (fp32, direct from x) + scatter
    float bv[4];
#pragma unroll
    for (int ni = 0; ni < 4; ni++)
        bv[ni] = bias[(size_t)e * DIM + n0 + wave_n + ni * 16 + lane15];
#pragma unroll
    for (int mi = 0; mi < 4; mi++) {
#pragma unroll
        for (int r4 = 0; r4 < 4; r4++) {
            int rl = wave_m + mi * 16 + quad * 4 + r4;
            if (rl < valid) {
                int orig = rowmap[pos0 + rl];
                const float* xrow = x + (size_t)orig * DIM + n0;
                float* orow = out + (size_t)orig * DIM + n0;
#pragma unroll
                for (int ni = 0; ni < 4; ni++) {
                    int col = wave_n + ni * 16 + lane15;
                    float v = acc[mi][ni][r4] + bv[ni];
                    v = v > 0.f ? v : 0.f;
                    orow[col] = xrow[col] + v;
                }
            }
        }
    }
}

// slow-but-correct fallback if workspace is too small
__global__ void k_naive(const float* __restrict__ x, const int* __restrict__ ids,
                        const float* __restrict__ W, const float* __restrict__ b,
                        float* __restrict__ out) {
    __shared__ float lx[DIM];
    int i = blockIdx.x;
    for (int t = threadIdx.x; t < DIM; t += blockDim.x) lx[t] = x[(size_t)i * DIM + t];
    __syncthreads();
    int e = ids[i];
    const float* We = W + (size_t)e * DIM * DIM;
    for (int n = threadIdx.x; n < DIM; n += blockDim.x) {
        const float* wr = We + (size_t)n * DIM;
        float acc = 0.f;
        for (int k = 0; k < DIM; k += 4) {
            float4 w4 = *(const float4*)(wr + k);
            acc += lx[k] * w4.x + lx[k + 1] * w4.y + lx[k + 2] * w4.z + lx[k + 3] * w4.w;
        }
        float v = acc + b[(size_t)e * DIM + n];
        v = v > 0.f ? v : 0.f;
        out[(size_t)i * DIM + n] = lx[n] + v;
    }
}

extern "C" void kernel_launch(void* const* d_in, const int* in_sizes, int n_in,
                              void* d_out, int out_size, void* d_ws, size_t ws_size,
                              hipStream_t stream) {
    const float* x   = (const float*)d_in[0];
    const int*   ids = (const int*)d_in[1];
    const float* W   = (const float*)d_in[2];
    const float* b   = (const float*)d_in[3];
    float* out = (float*)d_out;

    if (ws_size < WS_NEED) {
        k_naive<<<BATCH, 256, 0, stream>>>(x, ids, W, b, out);
        return;
    }

    char* wsb = (char*)d_ws;
    int*  wsi = (int*)wsb;
    int* rowmap = wsi + 512;
    int* zp = (int*)(wsb + ZP_BYTE_OFF);
    unsigned short* xb = (unsigned short*)(wsb + XB_BYTE_OFF);
    unsigned short* Wb = (unsigned short*)(wsb + WB_BYTE_OFF);

    k_prep<<<1 + NXBB + NCVTB, 512, 0, stream>>>(ids, wsi, rowmap,
                                                 (const float4*)x, (uint4*)xb,
                                                 (const float4*)W, (uint4*)Wb, zp);
    dim3 g(NBLK, MAX_TILES);
    k_gemm<<<g, 256, 0, stream>>>(x, xb, Wb, (const unsigned short*)zp,
                                  b, wsi, rowmap, out);
}

// Round 5
// 396.872 us; speedup vs baseline: 1.0875x; 1.0271x over previous
//
#include <hip/hip_runtime.h>
#include <hip/hip_bf16.h>
#include <stdint.h>

#define BATCH 8192
#define DIM   2048
#define NEXP  8
#define BM    128
#define BN    128
#define BK    32
#define NITER (DIM / BK)   // 64
#define MAX_TILES 72
#define NBLK  (DIM / BN)   // 16
#define NROWS 9216         // BATCH + max padding (8*128)
#define XROWB 2304         // x gather blocks: 9216 rows / 4 rows per block
#define WCVTB 2048         // W cvt blocks: 4.194M uint4-chunks / (512thr*4)

typedef __bf16 bf16x8 __attribute__((ext_vector_type(8)));
typedef float  f32x4  __attribute__((ext_vector_type(4)));

// ---- workspace layout ----
// metadata ints 0..511 (ntiles@48 tileExp@64 tilePos0@160 tileVal@256)
// rowmap @ int 512 (9216 ints, ends byte 38912)
// xg (bf16, compacted+padded rows) @ byte 40960 (37.75 MB)
// Wb (bf16) @ byte 37,789,696 (67 MB, ends exactly at WS_NEED)
#define XG_BYTE_OFF 40960ull
#define WB_BYTE_OFF 37789696ull
#define WS_NEED     104898560ull

#define AS1(p) ((const __attribute__((address_space(1))) void*)(p))
#define AS3(p) ((__attribute__((address_space(3))) void*)(p))

__device__ __forceinline__ unsigned f2bf2(float lo, float hi) {
    unsigned ul = __float_as_uint(lo), uh = __float_as_uint(hi);
    ul = (ul + 0x7FFFu + ((ul >> 16) & 1u)) >> 16;   // RNE
    uh = (uh + 0x7FFFu + ((uh >> 16) & 1u)) >> 16;
    return (uh << 16) | ul;
}

// single block: histogram -> per-expert wave-parallel scan (8 waves == NEXP)
// -> tile table -> rowmap (compacted position -> original row; -1 = padding).
// No atomics.
__global__ __launch_bounds__(512)
void k_plan(const int* __restrict__ ids, int* __restrict__ ws,
            int* __restrict__ rowmap) {
    __shared__ int sc[512 * NEXP];   // per-thread per-expert counts -> prefixes
    __shared__ int seg[NEXP];
    __shared__ int tot[NEXP];
    int t = threadIdx.x;
    int myids[16];
    int base = t * 16;               // each thread owns 16 consecutive rows
#pragma unroll
    for (int e = 0; e < NEXP; e++) sc[t * NEXP + e] = 0;
#pragma unroll
    for (int i = 0; i < 16; i++) {
        myids[i] = ids[base + i];
        sc[t * NEXP + myids[i]]++;
    }
    __syncthreads();
    // wave w computes exclusive prefix over the 512 counts of expert w
    {
        int w = t >> 6, l = t & 63;
        int e = w;
        int vals[8], sum = 0;
#pragma unroll
        for (int j = 0; j < 8; j++) { vals[j] = sc[(l * 8 + j) * NEXP + e]; sum += vals[j]; }
        int inc = sum;
        for (int d = 1; d < 64; d <<= 1) {
            int v = __shfl_up(inc, d, 64);
            if (l >= d) inc += v;
        }
        int run = inc - sum;         // exclusive
#pragma unroll
        for (int j = 0; j < 8; j++) { int v = vals[j]; sc[(l * 8 + j) * NEXP + e] = run; run += v; }
        if (l == 63) tot[e] = run;
    }
    __syncthreads();
    if (t == 0) {
        int pos = 0, mt = 0;
        for (int e = 0; e < NEXP; e++) {
            int c = tot[e];
            seg[e] = pos;
            int ntl = (c + BM - 1) / BM;
            for (int tt = 0; tt < ntl; tt++) {
                ws[64  + mt] = e;
                ws[160 + mt] = pos + tt * BM;
                int v = c - tt * BM;
                ws[256 + mt] = v < BM ? v : BM;
                mt++;
            }
            pos += ntl * BM;
        }
        ws[48] = mt;
    }
    __syncthreads();
    for (int i = t; i < NROWS; i += 512) rowmap[i] = -1;
    __syncthreads();                 // init drained before fills
#pragma unroll
    for (int i = 0; i < 16; i++) {
        int e = myids[i];
        int p = seg[e] + sc[t * NEXP + e]++;
        rowmap[p] = base + i;
    }
}

// streaming prep, balanced ~96 KB/block, zero atomics, zero cross-block deps:
//   blocks [0, XROWB)       : gather+convert 4 compacted rows each:
//                             xg[row] = bf16(x[rowmap[row]]) (zeros if -1);
//                             16B-in / 8B-out per thread per row, coalesced.
//   blocks [XROWB, +WCVTB)  : W fp32 -> bf16, 4 independent chunks/thread,
//                             32B-in / 16B-out, coalesced.
__global__ __launch_bounds__(512)
void k_prep(const float* __restrict__ x, const int* __restrict__ rowmap,
            unsigned short* __restrict__ xg,
            const float4* __restrict__ W, uint4* __restrict__ Wb) {
    int b = blockIdx.x;
    int t = threadIdx.x;
    if (b < XROWB) {
        int rm[4];
#pragma unroll
        for (int r = 0; r < 4; r++) rm[r] = rowmap[b * 4 + r];
#pragma unroll
        for (int r = 0; r < 4; r++) {
            int row = b * 4 + r;
            uint2* o = (uint2*)(xg + (size_t)row * DIM);
            if (rm[r] < 0) { o[t] = make_uint2(0, 0); continue; }
            float4 a = ((const float4*)(x + (size_t)rm[r] * DIM))[t];
            uint2 v;
            v.x = f2bf2(a.x, a.y);
            v.y = f2bf2(a.z, a.w);
            o[t] = v;
        }
        return;
    }
    size_t base = (size_t)(b - XROWB) * 2048;   // uint4 index
#pragma unroll
    for (int j = 0; j < 4; j++) {
        size_t o = base + (size_t)j * 512 + t;
        float4 a = W[o * 2], c = W[o * 2 + 1];
        uint4 v;
        v.x = f2bf2(a.x, a.y);  v.y = f2bf2(a.z, a.w);
        v.z = f2bf2(c.x, c.y);  v.w = f2bf2(c.z, c.w);
        Wb[o] = v;
    }
}

// grouped GEMM — round-0 PROVEN version (131 us measured): 128x128 tile,
// 4 waves (2x2 of 64x64), BK=32, DOUBLE-BUFFERED LDS, single barrier per
// iter (drains vmcnt(0)); prefetch tile i+1 during compute of tile i.
// Both A and B staged via global_load_lds from CONTIGUOUS sources (xg is
// compacted). Swizzle: 16B chunk at LDS position p of row r holds logical
// chunk p ^ ((r>>1)&3) -> 2-way (free) bank aliasing on ds_read_b128,
// applied on the staging SOURCE address (dest stays wave-uniform linear).
// Grid dim3(16,72): XCD = nb%8 -> each 512KB B-panel owned by one XCD,
// L2-resident across that expert's m-tiles (proven round-0 mapping).
__launch_bounds__(256)
__global__ void k_gemm(const unsigned short* __restrict__ xg,
                       const unsigned short* __restrict__ Wb,
                       const float* __restrict__ bias,
                       const int* __restrict__ ws, const int* __restrict__ rowmap,
                       float* __restrict__ out) {
    int mt = blockIdx.y;
    if (mt >= ws[48]) return;
    int e     = ws[64  + mt];
    int pos0  = ws[160 + mt];
    int valid = ws[256 + mt];
    int n0 = blockIdx.x * BN;

    __shared__ unsigned short lds[2][8192];  // [buf][0..4095]=A, [4096..8191]=B; 32 KB

    int tid = threadIdx.x;
    int w = tid >> 6, l = tid & 63;
    int lane15 = l & 15, quad = l >> 4;
    int wave_m = (w >> 1) * 64, wave_n = (w & 1) * 64;

    const unsigned short* Abase = xg + (size_t)pos0 * DIM;
    const unsigned short* Bbase = Wb + (size_t)e * DIM * DIM + (size_t)n0 * DIM;

    // staging source offsets (shorts), invariant across K except +k0.
    // tile side = 512 chunks of 16B; wave w stages chunks [w*128, w*128+128)
    // in 2 issues of 64. chunk c: row=c>>2, dest pos=c&3, src q = pos^((row>>1)&3)
    int srcOff[2];
#pragma unroll
    for (int j = 0; j < 2; j++) {
        int c = w * 128 + j * 64 + l;
        int row = c >> 2, pos = c & 3;
        int q = pos ^ ((row >> 1) & 3);
        srcOff[j] = row * DIM + q * 8;
    }

    // fragment read offsets (shorts), loop-invariant.
    int swz = (quad ^ ((lane15 >> 1) & 3)) * 8;
    int afOff[4], bfOff[4];
#pragma unroll
    for (int mi = 0; mi < 4; mi++)
        afOff[mi] = (wave_m + mi * 16 + lane15) * BK + swz;
#pragma unroll
    for (int ni = 0; ni < 4; ni++)
        bfOff[ni] = 4096 + (wave_n + ni * 16 + lane15) * BK + swz;

    f32x4 acc[4][4];
#pragma unroll
    for (int i = 0; i < 4; i++)
#pragma unroll
        for (int j = 0; j < 4; j++) acc[i][j] = (f32x4){0.f, 0.f, 0.f, 0.f};

#define ISSUE(buf, k0)                                                          \
    do {                                                                        \
        _Pragma("unroll")                                                       \
        for (int j = 0; j < 2; j++) {                                           \
            __builtin_amdgcn_global_load_lds(                                   \
                AS1(Abase + (k0) + srcOff[j]),                                  \
                AS3(&lds[buf][w * 1024 + j * 512]), 16, 0, 0);                  \
            __builtin_amdgcn_global_load_lds(                                   \
                AS1(Bbase + (k0) + srcOff[j]),                                  \
                AS3(&lds[buf][4096 + w * 1024 + j * 512]), 16, 0, 0);           \
        }                                                                       \
    } while (0)

    ISSUE(0, 0);
    int cur = 0;
    for (int i = 0; i < NITER; ++i) {
        __syncthreads();   // drains vmcnt(0): loads(i) complete (in flight
                           // during compute(i-1)); all compute(i-1) done.
        if (i + 1 < NITER) {
            int k0n = (i + 1) * BK;
            ISSUE(cur ^ 1, k0n);
        }
        bf16x8 af[4], bf[4];
#pragma unroll
        for (int mi = 0; mi < 4; mi++)
            af[mi] = *(const bf16x8*)(&lds[cur][afOff[mi]]);
#pragma unroll
        for (int ni = 0; ni < 4; ni++)
            bf[ni] = *(const bf16x8*)(&lds[cur][bfOff[ni]]);
#pragma unroll
        for (int mi = 0; mi < 4; mi++)
#pragma unroll
            for (int ni = 0; ni < 4; ni++)
                acc[mi][ni] = __builtin_amdgcn_mfma_f32_16x16x32_bf16(
                    af[mi], bf[ni], acc[mi][ni], 0, 0, 0);
        cur ^= 1;
    }
#undef ISSUE

    // epilogue: bias + relu + residual(from xg, bf16, contiguous) + scatter
    float bv[4];
#pragma unroll
    for (int ni = 0; ni < 4; ni++)
        bv[ni] = bias[(size_t)e * DIM + n0 + wave_n + ni * 16 + lane15];
#pragma unroll
    for (int mi = 0; mi < 4; mi++) {
#pragma unroll
        for (int r4 = 0; r4 < 4; r4++) {
            int rl = wave_m + mi * 16 + quad * 4 + r4;
            if (rl < valid) {
                int orig = rowmap[pos0 + rl];
                const unsigned short* xrow = xg + (size_t)(pos0 + rl) * DIM + n0;
                float* orow = out + (size_t)orig * DIM + n0;
#pragma unroll
                for (int ni = 0; ni < 4; ni++) {
                    int col = wave_n + ni * 16 + lane15;
                    float xv = __uint_as_float((unsigned)xrow[col] << 16);
                    float v = acc[mi][ni][r4] + bv[ni];
                    v = v > 0.f ? v : 0.f;
                    orow[col] = xv + v;
                }
            }
        }
    }
}

// slow-but-correct fallback if workspace is too small
__global__ void k_naive(const float* __restrict__ x, const int* __restrict__ ids,
                        const float* __restrict__ W, const float* __restrict__ b,
                        float* __restrict__ out) {
    __shared__ float lx[DIM];
    int i = blockIdx.x;
    for (int t = threadIdx.x; t < DIM; t += blockDim.x) lx[t] = x[(size_t)i * DIM + t];
    __syncthreads();
    int e = ids[i];
    const float* We = W + (size_t)e * DIM * DIM;
    for (int n = threadIdx.x; n < DIM; n += blockDim.x) {
        const float* wr = We + (size_t)n * DIM;
        float acc = 0.f;
        for (int k = 0; k < DIM; k += 4) {
            float4 w4 = *(const float4*)(wr + k);
            acc += lx[k] * w4.x + lx[k + 1] * w4.y + lx[k + 2] * w4.z + lx[k + 3] * w4.w;
        }
        float v = acc + b[(size_t)e * DIM + n];
        v = v > 0.f ? v : 0.f;
        out[(size_t)i * DIM + n] = lx[n] + v;
    }
}

extern "C" void kernel_launch(void* const* d_in, const int* in_sizes, int n_in,
                              void* d_out, int out_size, void* d_ws, size_t ws_size,
                              hipStream_t stream) {
    const float* x   = (const float*)d_in[0];
    const int*   ids = (const int*)d_in[1];
    const float* W   = (const float*)d_in[2];
    const float* b   = (const float*)d_in[3];
    float* out = (float*)d_out;

    if (ws_size < WS_NEED) {
        k_naive<<<BATCH, 256, 0, stream>>>(x, ids, W, b, out);
        return;
    }

    char* wsb = (char*)d_ws;
    int*  wsi = (int*)wsb;
    int* rowmap = wsi + 512;
    unsigned short* xg = (unsigned short*)(wsb + XG_BYTE_OFF);
    unsigned short* Wb = (unsigned short*)(wsb + WB_BYTE_OFF);

    k_plan<<<1, 512, 0, stream>>>(ids, wsi, rowmap);
    k_prep<<<XROWB + WCVTB, 512, 0, stream>>>(x, rowmap, xg,
                                              (const float4*)W, (uint4*)Wb);
    dim3 g(NBLK, MAX_TILES);
    k_gemm<<<g, 256, 0, stream>>>(xg, Wb, b, wsi, rowmap, out);
}